// Round 7
// baseline (685.685 us; speedup 1.0000x reference)
//
#include <hip/hip_runtime.h>

typedef __attribute__((ext_vector_type(8))) short short8;
typedef __attribute__((ext_vector_type(4))) short short4v;
typedef __attribute__((ext_vector_type(4))) float floatx4;
typedef __attribute__((ext_vector_type(4))) unsigned int uint4v;

#define MFMA_BF16 __builtin_amdgcn_mfma_f32_16x16x32_bf16
#define LOG2E 1.44269504088896340736f

// K=16 bf16 MFMA (attn_ca only). Guarded so the HIP host pass never parses it.
__device__ inline floatx4 MFMA16(short4v a, short4v b, floatx4 c){
#if defined(__HIP_DEVICE_COMPILE__)
  return __builtin_amdgcn_mfma_f32_16x16x16bf16_1k(a, b, c, 0, 0, 0);
#else
  return c;
#endif
}

__device__ inline unsigned short f2bf(float x){
  unsigned int u = __float_as_uint(x);
  u += 0x7fffu + ((u >> 16) & 1u);
  return (unsigned short)(u >> 16);
}
__device__ inline float bf2f(unsigned short h){
  return __uint_as_float(((unsigned int)h) << 16);
}
// truncating bf16 pair pack: (hi<<16)|lo, 1 instr
__device__ inline unsigned pack_bf(float lo, float hi){
  return __builtin_amdgcn_perm(__float_as_uint(hi), __float_as_uint(lo), 0x07060302u);
}

__device__ inline float wave_sum(float v){
  #pragma unroll
  for(int m=32;m>=1;m>>=1) v += __shfl_xor(v,m);
  return v;
}

// ---------------- GroupNorm1 (stats+apply+transpose). x:(BT,C,HW) -> xs:(BT,HW,C) f32
__global__ __launch_bounds__(256) void gn1_kernel(const float* __restrict__ x,
    const float* __restrict__ w, const float* __restrict__ b, float* __restrict__ xs){
  int g = blockIdx.x, bt = blockIdx.y, tid = threadIdx.x;
  const float* xp = x + ((size_t)bt*512 + g*16)*1024;
  float s=0.f, s2=0.f;
  #pragma unroll
  for(int it=0; it<16; ++it){
    float4 v = *(const float4*)(xp + it*1024 + tid*4);
    s  += v.x+v.y+v.z+v.w;
    s2 += v.x*v.x+v.y*v.y+v.z*v.z+v.w*v.w;
  }
  __shared__ float red[8];
  s = wave_sum(s); s2 = wave_sum(s2);
  int wid = tid>>6;
  if((tid&63)==0){ red[wid*2]=s; red[wid*2+1]=s2; }
  __syncthreads();
  s  = red[0]+red[2]+red[4]+red[6];
  s2 = red[1]+red[3]+red[5]+red[7];
  float mean = s * (1.f/16384.f);
  float var  = s2 * (1.f/16384.f) - mean*mean;
  float rinv = rsqrtf(var + 1e-5f);
  int c = tid & 15, h0 = tid >> 4;
  float sc = w[g*16+c]*rinv;
  float sh = b[g*16+c] - mean*sc;
  const float* xcol = xp + (size_t)c*1024;
  float* op = xs + (size_t)bt*1024*512 + g*16 + c;
  #pragma unroll 4
  for(int it=0; it<64; ++it){
    int hw = h0 + it*16;
    op[(size_t)hw*512] = xcol[hw]*sc + sh;
  }
}

// ---------------- Dual LayerNorm per row: vnb (bf16, lnv params), lnlb (bf16, lnl params)
__global__ __launch_bounds__(256) void ln_dual_kernel(const float* __restrict__ xs,
    const float* __restrict__ lvw, const float* __restrict__ lvb,
    const float* __restrict__ llw, const float* __restrict__ llb,
    unsigned short* __restrict__ vnb, unsigned short* __restrict__ lnlb){
  int wid = threadIdx.x>>6, l = threadIdx.x&63;
  size_t row = (size_t)blockIdx.x*4 + wid;
  const float* xp = xs + row*512;
  float4 a = *(const float4*)(xp + l*4);
  float4 c = *(const float4*)(xp + 256 + l*4);
  float s  = a.x+a.y+a.z+a.w + c.x+c.y+c.z+c.w;
  float s2 = a.x*a.x+a.y*a.y+a.z*a.z+a.w*a.w + c.x*c.x+c.y*c.y+c.z*c.z+c.w*c.w;
  s = wave_sum(s); s2 = wave_sum(s2);
  float mean = s*(1.f/512.f);
  float rinv = rsqrtf(s2*(1.f/512.f) - mean*mean + 1e-5f);
  int c0 = l*4, c1 = 256 + l*4;
  float y[8] = {(a.x-mean)*rinv,(a.y-mean)*rinv,(a.z-mean)*rinv,(a.w-mean)*rinv,
                (c.x-mean)*rinv,(c.y-mean)*rinv,(c.z-mean)*rinv,(c.w-mean)*rinv};
  ushort4 h;
  h.x=f2bf(y[0]*lvw[c0+0]+lvb[c0+0]); h.y=f2bf(y[1]*lvw[c0+1]+lvb[c0+1]);
  h.z=f2bf(y[2]*lvw[c0+2]+lvb[c0+2]); h.w=f2bf(y[3]*lvw[c0+3]+lvb[c0+3]);
  *(ushort4*)(vnb + row*512 + c0) = h;
  h.x=f2bf(y[4]*lvw[c1+0]+lvb[c1+0]); h.y=f2bf(y[5]*lvw[c1+1]+lvb[c1+1]);
  h.z=f2bf(y[6]*lvw[c1+2]+lvb[c1+2]); h.w=f2bf(y[7]*lvw[c1+3]+lvb[c1+3]);
  *(ushort4*)(vnb + row*512 + c1) = h;
  h.x=f2bf(y[0]*llw[c0+0]+llb[c0+0]); h.y=f2bf(y[1]*llw[c0+1]+llb[c0+1]);
  h.z=f2bf(y[2]*llw[c0+2]+llb[c0+2]); h.w=f2bf(y[3]*llw[c0+3]+llb[c0+3]);
  *(ushort4*)(lnlb + row*512 + c0) = h;
  h.x=f2bf(y[4]*llw[c1+0]+llb[c1+0]); h.y=f2bf(y[5]*llw[c1+1]+llb[c1+1]);
  h.z=f2bf(y[6]*llw[c1+2]+llb[c1+2]); h.w=f2bf(y[7]*llw[c1+3]+llb[c1+3]);
  *(ushort4*)(lnlb + row*512 + c1) = h;
}

// ---------------- fused GN2-apply + LayerNorm (ca_lnv): xs2b bf16 + raw sums -> vn2b bf16
__global__ __launch_bounds__(256) void gn2ln_kernel(const unsigned short* __restrict__ xs2b,
    const float* __restrict__ st,
    const float* __restrict__ gw, const float* __restrict__ gb,
    const float* __restrict__ lw, const float* __restrict__ lb,
    unsigned short* __restrict__ vn2b){
  int wid = threadIdx.x>>6, l = threadIdx.x&63;
  size_t row = (size_t)blockIdx.x*4 + wid;
  int bt = (int)(row >> 10);
  const unsigned short* xp = xs2b + row*512;
  ushort4 ua = *(const ushort4*)(xp + l*4);
  ushort4 uc = *(const ushort4*)(xp + 256 + l*4);
  int c0 = l*4, c1 = 256 + l*4;
  int g0 = c0>>4, g1 = c1>>4;
  float sA = st[(bt*32+g0)*2],   qA = st[(bt*32+g0)*2+1];
  float sB = st[(bt*32+g1)*2],   qB = st[(bt*32+g1)*2+1];
  float m0 = sA*(1.f/16384.f);
  float r0 = rsqrtf(qA*(1.f/16384.f) - m0*m0 + 1e-5f);
  float m1 = sB*(1.f/16384.f);
  float r1 = rsqrtf(qB*(1.f/16384.f) - m1*m1 + 1e-5f);
  float y[8];
  y[0]=(bf2f(ua.x)-m0)*r0*gw[c0+0]+gb[c0+0]; y[1]=(bf2f(ua.y)-m0)*r0*gw[c0+1]+gb[c0+1];
  y[2]=(bf2f(ua.z)-m0)*r0*gw[c0+2]+gb[c0+2]; y[3]=(bf2f(ua.w)-m0)*r0*gw[c0+3]+gb[c0+3];
  y[4]=(bf2f(uc.x)-m1)*r1*gw[c1+0]+gb[c1+0]; y[5]=(bf2f(uc.y)-m1)*r1*gw[c1+1]+gb[c1+1];
  y[6]=(bf2f(uc.z)-m1)*r1*gw[c1+2]+gb[c1+2]; y[7]=(bf2f(uc.w)-m1)*r1*gw[c1+3]+gb[c1+3];
  float s=0.f, s2=0.f;
  #pragma unroll
  for(int i=0;i<8;++i){ s += y[i]; s2 += y[i]*y[i]; }
  s = wave_sum(s); s2 = wave_sum(s2);
  float mean = s*(1.f/512.f);
  float rinv = rsqrtf(s2*(1.f/512.f) - mean*mean + 1e-5f);
  ushort4 h;
  h.x=f2bf((y[0]-mean)*rinv*lw[c0+0]+lb[c0+0]); h.y=f2bf((y[1]-mean)*rinv*lw[c0+1]+lb[c0+1]);
  h.z=f2bf((y[2]-mean)*rinv*lw[c0+2]+lb[c0+2]); h.w=f2bf((y[3]-mean)*rinv*lw[c0+3]+lb[c0+3]);
  *(ushort4*)(vn2b + row*512 + c0) = h;
  h.x=f2bf((y[4]-mean)*rinv*lw[c1+0]+lb[c1+0]); h.y=f2bf((y[5]-mean)*rinv*lw[c1+1]+lb[c1+1]);
  h.z=f2bf((y[6]-mean)*rinv*lw[c1+2]+lb[c1+2]); h.w=f2bf((y[7]-mean)*rinv*lw[c1+3]+lb[c1+3]);
  *(ushort4*)(vn2b + row*512 + c1) = h;
}

// ---------------- context LayerNorm (ca_lnl) -> bf16, 154 rows
__global__ __launch_bounds__(256) void ctxln_kernel(const float* __restrict__ ctx,
    const float* __restrict__ lw, const float* __restrict__ lb, unsigned short* __restrict__ out){
  int wid = threadIdx.x>>6, l = threadIdx.x&63;
  int row = blockIdx.x*4 + wid;
  if(row >= 154) return;
  const float* xp = ctx + (size_t)row*512;
  float4 a = *(const float4*)(xp + l*4);
  float4 c = *(const float4*)(xp + 256 + l*4);
  float s  = a.x+a.y+a.z+a.w + c.x+c.y+c.z+c.w;
  float s2 = a.x*a.x+a.y*a.y+a.z*a.z+a.w*a.w + c.x*c.x+c.y*c.y+c.z*c.z+c.w*c.w;
  s = wave_sum(s); s2 = wave_sum(s2);
  float mean = s*(1.f/512.f);
  float rinv = rsqrtf(s2*(1.f/512.f) - mean*mean + 1e-5f);
  int c0 = l*4, c1 = 256 + l*4;
  ushort4 h;
  h.x=f2bf((a.x-mean)*rinv*lw[c0+0]+lb[c0+0]); h.y=f2bf((a.y-mean)*rinv*lw[c0+1]+lb[c0+1]);
  h.z=f2bf((a.z-mean)*rinv*lw[c0+2]+lb[c0+2]); h.w=f2bf((a.w-mean)*rinv*lw[c0+3]+lb[c0+3]);
  *(ushort4*)(out + (size_t)row*512 + c0) = h;
  h.x=f2bf((c.x-mean)*rinv*lw[c1+0]+lb[c1+0]); h.y=f2bf((c.y-mean)*rinv*lw[c1+1]+lb[c1+1]);
  h.z=f2bf((c.z-mean)*rinv*lw[c1+2]+lb[c1+2]); h.w=f2bf((c.w-mean)*rinv*lw[c1+3]+lb[c1+3]);
  *(ushort4*)(out + (size_t)row*512 + c1) = h;
}

// ---------------- weight fp32 -> bf16 (8 weights of 512x512)
__global__ __launch_bounds__(256) void cvtw_kernel(const float* s0, const float* s1, const float* s2,
    const float* s3, const float* s4, const float* s5, const float* s6, const float* s7,
    unsigned short* __restrict__ dst){
  const float* srcs[8] = {s0,s1,s2,s3,s4,s5,s6,s7};
  int w = blockIdx.y;
  const float* src = srcs[w];
  int i = (blockIdx.x*256 + threadIdx.x)*4;
  float4 v = *(const float4*)(src + i);
  ushort4 h; h.x=f2bf(v.x); h.y=f2bf(v.y); h.z=f2bf(v.z); h.w=f2bf(v.w);
  *(ushort4*)(dst + (size_t)w*262144 + i) = h;
}

// ---------------- bf16 MFMA GEMM: wave tile 64m x 64n. out[M,512] = A[M,512] @ W[512,512]^T
// MODE 0: outb = bf16((acc+bias)*scale)
// MODE 1: outb = bf16(r1f + bf(rb) + gamma*(acc+bias)); fused GN2 partial sums -> atomicAdd st2
// MODE 2: outf[bt,c,hw] = bf(rb) + gamma*(acc+bias)     [transposed f32 final store]
// MODE 3: outb transposed bf16: VT[(m>>10)*512+col][m&1023]
// MODE 4: outb = V2T[(cb*512+col)*128 + key], cb=m>=77,key=m-77cb (M=154)
template<int MODE>
__global__ __launch_bounds__(256) void gemm64_kernel(const unsigned short* __restrict__ A,
    const unsigned short* __restrict__ W, const float* __restrict__ bias, int M, float scale,
    unsigned short* __restrict__ outb, float* __restrict__ outf,
    const float* __restrict__ r1f, const unsigned short* __restrict__ rb,
    const float* __restrict__ gamma, float* __restrict__ st2){
  int wid = threadIdx.x>>6, l = threadIdx.x&63, quad = l>>4, ln16 = l&15;
  int m0 = blockIdx.x*64;
  int n0 = blockIdx.y*256 + wid*64;
  const unsigned short* Ap[4];
  #pragma unroll
  for(int mf=0;mf<4;++mf){
    int arow = m0 + mf*16 + ln16; if(arow > M-1) arow = M-1;
    Ap[mf] = A + (size_t)arow*512 + quad*8;
  }
  const unsigned short* Wp = W + (size_t)(n0+ln16)*512 + quad*8;
  floatx4 acc[4][4];
  #pragma unroll
  for(int mf=0;mf<4;++mf)
    #pragma unroll
    for(int nf=0;nf<4;++nf) acc[mf][nf] = (floatx4){0,0,0,0};
  #pragma unroll 2
  for(int k=0;k<512;k+=32){
    short8 av[4], wv[4];
    #pragma unroll
    for(int mf=0;mf<4;++mf) av[mf] = *(const short8*)(Ap[mf] + k);
    #pragma unroll
    for(int nf=0;nf<4;++nf) wv[nf] = *(const short8*)(Wp + nf*16*512 + k);
    #pragma unroll
    for(int mf=0;mf<4;++mf)
      #pragma unroll
      for(int nf=0;nf<4;++nf)
        acc[mf][nf] = MFMA_BF16(av[mf], wv[nf], acc[mf][nf], 0,0,0);
  }
  if(MODE==1){
    int bt = m0 >> 10;
    #pragma unroll
    for(int nf=0;nf<4;++nf){
      int col = n0 + nf*16 + ln16;
      float bv = bias[col];
      float gv = gamma[col];
      float s=0.f, s2=0.f;
      #pragma unroll
      for(int mf=0;mf<4;++mf){
        int mb = m0 + mf*16 + quad*4;
        #pragma unroll
        for(int r=0;r<4;++r){
          size_t ix = (size_t)(mb+r)*512 + col;
          float o = r1f[ix] + bf2f(rb[ix]) + gv*(acc[mf][nf][r] + bv);
          outb[ix] = f2bf(o);
          s += o; s2 += o*o;
        }
      }
      s = wave_sum(s); s2 = wave_sum(s2);
      if(l == 0){
        int g = (n0 + nf*16) >> 4;
        atomicAdd(&st2[(bt*32+g)*2],   s);
        atomicAdd(&st2[(bt*32+g)*2+1], s2);
      }
    }
    return;
  }
  #pragma unroll
  for(int mf=0;mf<4;++mf){
    int mb = m0 + mf*16 + quad*4;
    #pragma unroll
    for(int nf=0;nf<4;++nf){
      int col = n0 + nf*16 + ln16;
      float bv = bias[col];
      if(MODE==0){
        #pragma unroll
        for(int r=0;r<4;++r){
          int m = mb + r;
          if(m < M) outb[(size_t)m*512 + col] = f2bf((acc[mf][nf][r] + bv)*scale);
        }
      } else if(MODE==2){
        float gv = gamma[col];
        int bt = mb >> 10;
        int hw0 = mb & 1023;
        float4 ov;
        ov.x = bf2f(rb[(size_t)(mb+0)*512+col]) + gv*(acc[mf][nf][0]+bv);
        ov.y = bf2f(rb[(size_t)(mb+1)*512+col]) + gv*(acc[mf][nf][1]+bv);
        ov.z = bf2f(rb[(size_t)(mb+2)*512+col]) + gv*(acc[mf][nf][2]+bv);
        ov.w = bf2f(rb[(size_t)(mb+3)*512+col]) + gv*(acc[mf][nf][3]+bv);
        *(float4*)(outf + (size_t)bt*524288 + (size_t)col*1024 + hw0) = ov;
      } else if(MODE==3){
        int bf = mb >> 10;
        int hw0 = mb & 1023;
        ushort4 h;
        h.x = f2bf(acc[mf][nf][0]+bv); h.y = f2bf(acc[mf][nf][1]+bv);
        h.z = f2bf(acc[mf][nf][2]+bv); h.w = f2bf(acc[mf][nf][3]+bv);
        *(ushort4*)(outb + ((size_t)bf*512 + col)*1024 + hw0) = h;
      } else if(MODE==4){
        #pragma unroll
        for(int r=0;r<4;++r){
          int m = mb + r;
          if(m < M){
            int cb = (m >= 77) ? 1 : 0;
            int key = m - 77*cb;
            outb[((size_t)cb*512 + col)*128 + key] = f2bf(acc[mf][nf][r] + bv);
          }
        }
      }
    }
  }
}

// ---------------- spatial flash attention v6: PV at K=32 via permuted V^T LDS columns.
// vt col c (within 32-key block) holds key ((c&4)<<2) + ((c>>3)*4) + (c&3); the two 16-key
// score groups then pack directly into one 16x16x32 B-fragment (no cross-lane ops).
__global__ __launch_bounds__(256,4) void attn_sp_kernel(const unsigned short* __restrict__ Q,
    const unsigned short* __restrict__ K, const unsigned short* __restrict__ VT,
    unsigned short* __restrict__ O){
  int id = blockIdx.x;
  int hb = id & 127, qt = id >> 7;
  int head = hb >> 4, bz = hb & 15;
  int b = bz >> 3, idx = bz & 7;
  int tid = threadIdx.x, wid = tid>>6, l = tid&63, quad = l>>4, ln16 = l&15;
  __shared__ unsigned short vt[2][64*72];     // [buf][dim][key-permuted]
  __shared__ unsigned short kt[2][64*72];     // [buf][key][dim]
  size_t qbase = (size_t)bz*1024 + qt*128 + wid*32 + ln16;
  short8 qb[2][2];
  #pragma unroll
  for(int grp=0;grp<2;++grp){
    const unsigned short* qp = Q + (qbase + grp*16)*512 + head*64 + quad*8;
    qb[grp][0] = *(const short8*)(qp);
    qb[grp][1] = *(const short8*)(qp + 32);
  }
  floatx4 o[2][4];
  #pragma unroll
  for(int g=0;g<2;++g)
    #pragma unroll
    for(int d=0;d<4;++d) o[g][d] = (floatx4){0,0,0,0};
  float lr[2] = {0.f,0.f};
  int nch = idx ? 32 : 16;
  int f0  = idx ? (idx-1) : 0;
  int sr = tid>>2, sk0 = (tid&3)*16;
  int vbase = (sk0 & 32) + ((sk0 & 16) >> 2);   // 0,4,32,36
  short8 pv0, pv1, pk0, pk1;
  {
    const unsigned short* vp = VT + (((size_t)(b*8+f0)*512) + head*64 + sr)*1024 + sk0;
    pv0 = *(const short8*)(vp); pv1 = *(const short8*)(vp + 8);
    const unsigned short* kp = K + (((size_t)(b*8+f0))*1024 + sr)*512 + head*64 + sk0;
    pk0 = *(const short8*)(kp); pk1 = *(const short8*)(kp + 8);
  }
  for(int ch=0; ch<nch; ++ch){
    int bf_ = ch & 1;
    { // permuted V^T staging: 4x b64 at cols vbase + {0,8,16,24}
      uint4v v0 = __builtin_bit_cast(uint4v, pv0);
      uint4v v1 = __builtin_bit_cast(uint4v, pv1);
      unsigned short* vtb = &vt[bf_][0] + sr*72;
      uint2 w;
      w.x = v0.x; w.y = v0.y; *(uint2*)(vtb + vbase)      = w;
      w.x = v0.z; w.y = v0.w; *(uint2*)(vtb + vbase + 8)  = w;
      w.x = v1.x; w.y = v1.y; *(uint2*)(vtb + vbase + 16) = w;
      w.x = v1.z; w.y = v1.w; *(uint2*)(vtb + vbase + 24) = w;
      *(short8*)(&kt[bf_][0] + sr*72 + sk0)     = pk0;
      *(short8*)(&kt[bf_][0] + sr*72 + sk0 + 8) = pk1;
    }
    if(ch+1 < nch){
      int f = f0 + ((ch+1)>>4);
      int kk0 = ((ch+1)&15)*64;
      const unsigned short* vp = VT + (((size_t)(b*8+f)*512) + head*64 + sr)*1024 + kk0 + sk0;
      pv0 = *(const short8*)(vp); pv1 = *(const short8*)(vp + 8);
      const unsigned short* kp = K + (((size_t)(b*8+f))*1024 + kk0 + sr)*512 + head*64 + sk0;
      pk0 = *(const short8*)(kp); pk1 = *(const short8*)(kp + 8);
    }
    __syncthreads();
    #pragma unroll
    for(int t=0; t<2; ++t){
      const unsigned short* krA = &kt[bf_][0] + (t*32+ln16)*72 + quad*8;
      const unsigned short* krB = krA + 16*72;
      short8 ka0 = *(const short8*)(krA);
      short8 ka1 = *(const short8*)(krA + 32);
      short8 kb0 = *(const short8*)(krB);
      short8 kb1 = *(const short8*)(krB + 32);
      short8 va[4];
      #pragma unroll
      for(int dc=0; dc<4; ++dc)
        va[dc] = *(const short8*)(&vt[bf_][0] + (dc*16+ln16)*72 + t*32 + quad*8);
      #pragma unroll
      for(int grp=0; grp<2; ++grp){
        floatx4 sA = {0,0,0,0}, sB = {0,0,0,0};
        sA = MFMA_BF16(ka0, qb[grp][0], sA, 0,0,0);
        sA = MFMA_BF16(ka1, qb[grp][1], sA, 0,0,0);
        sB = MFMA_BF16(kb0, qb[grp][0], sB, 0,0,0);
        sB = MFMA_BF16(kb1, qb[grp][1], sB, 0,0,0);
        float a0 = __builtin_amdgcn_exp2f(sA[0]);
        float a1 = __builtin_amdgcn_exp2f(sA[1]);
        float a2 = __builtin_amdgcn_exp2f(sA[2]);
        float a3 = __builtin_amdgcn_exp2f(sA[3]);
        float b0 = __builtin_amdgcn_exp2f(sB[0]);
        float b1 = __builtin_amdgcn_exp2f(sB[1]);
        float b2 = __builtin_amdgcn_exp2f(sB[2]);
        float b3 = __builtin_amdgcn_exp2f(sB[3]);
        lr[grp] += ((a0+a1)+(a2+a3)) + ((b0+b1)+(b2+b3));
        uint4v pu;
        pu.x = pack_bf(a0,a1); pu.y = pack_bf(a2,a3);
        pu.z = pack_bf(b0,b1); pu.w = pack_bf(b2,b3);
        short8 pb = __builtin_bit_cast(short8, pu);
        #pragma unroll
        for(int dc=0; dc<4; ++dc)
          o[grp][dc] = MFMA_BF16(va[dc], pb, o[grp][dc], 0,0,0);
      }
    }
  }
  #pragma unroll
  for(int grp=0; grp<2; ++grp){
    float lt = lr[grp];
    lt += __shfl_xor(lt, 16); lt += __shfl_xor(lt, 32);
    float inv = __builtin_amdgcn_rcpf(lt);
    size_t orow = qbase + grp*16;
    unsigned short* op = O + orow*512 + head*64 + quad*4;
    #pragma unroll
    for(int dc=0; dc<4; ++dc){
      uint2 pk;
      pk.x = pack_bf(o[grp][dc][0]*inv, o[grp][dc][1]*inv);
      pk.y = pack_bf(o[grp][dc][2]*inv, o[grp][dc][3]*inv);
      *(uint2*)(op + dc*16) = pk;
    }
  }
}

// ---------------- cross attention v5: 77 keys (2 chunks of 64, masked), 32 q/wave, dbuf
__global__ __launch_bounds__(256) void attn_ca_kernel(const unsigned short* __restrict__ Q,
    const unsigned short* __restrict__ K2, const unsigned short* __restrict__ V2T,
    unsigned short* __restrict__ O){
  int id = blockIdx.x;
  int hb = id & 127, qt = id >> 7;
  int head = hb >> 4, bt = hb & 15;
  int cb = bt & 1;
  int tid = threadIdx.x, wid = tid>>6, l = tid&63, quad = l>>4, ln16 = l&15;
  __shared__ unsigned short vt[2][64*72];
  __shared__ unsigned short kt[2][64*72];
  size_t qbase = (size_t)bt*1024 + qt*128 + wid*32 + ln16;
  short8 qb[2][2];
  #pragma unroll
  for(int grp=0;grp<2;++grp){
    const unsigned short* qp = Q + (qbase + grp*16)*512 + head*64 + quad*8;
    qb[grp][0] = *(const short8*)(qp);
    qb[grp][1] = *(const short8*)(qp + 32);
  }
  floatx4 o[2][4];
  #pragma unroll
  for(int g=0;g<2;++g)
    #pragma unroll
    for(int d=0;d<4;++d) o[g][d] = (floatx4){0,0,0,0};
  float lr[2] = {0.f,0.f};
  int sr = tid>>2, sc0 = (tid&3)*16;
  short8 pv0, pv1, pk0, pk1;
  {
    const unsigned short* vp = V2T + (((size_t)cb*512) + head*64 + sr)*128 + sc0;
    pv0 = *(const short8*)(vp); pv1 = *(const short8*)(vp + 8);
    const unsigned short* kp = K2 + ((size_t)cb*77 + sr)*512 + head*64 + sc0;
    pk0 = *(const short8*)(kp); pk1 = *(const short8*)(kp + 8);
  }
  for(int ch=0; ch<2; ++ch){
    int bf_ = ch & 1;
    int kk0 = ch*64;
    *(short8*)(&vt[bf_][0] + sr*72 + sc0)     = pv0;
    *(short8*)(&vt[bf_][0] + sr*72 + sc0 + 8) = pv1;
    *(short8*)(&kt[bf_][0] + sr*72 + sc0)     = pk0;
    *(short8*)(&kt[bf_][0] + sr*72 + sc0 + 8) = pk1;
    if(ch == 0){
      const unsigned short* vp = V2T + (((size_t)cb*512) + head*64 + sr)*128 + 64 + sc0;
      pv0 = *(const short8*)(vp); pv1 = *(const short8*)(vp + 8);
      const unsigned short* kp = K2 + ((size_t)cb*77 + 64 + sr)*512 + head*64 + sc0;
      pk0 = *(const short8*)(kp); pk1 = *(const short8*)(kp + 8);
    }
    __syncthreads();
    #pragma unroll
    for(int g=0; g<4; ++g){
      int kg = kk0 + g*16 + quad*4;
      const unsigned short* kr = &kt[bf_][0] + (g*16+ln16)*72 + quad*8;
      short8 k0 = *(const short8*)(kr);
      short8 k1 = *(const short8*)(kr + 32);
      short4v va[4];
      #pragma unroll
      for(int dc=0; dc<4; ++dc)
        va[dc] = *(const short4v*)(&vt[bf_][0] + (dc*16+ln16)*72 + g*16 + quad*4);
      #pragma unroll
      for(int grp=0; grp<2; ++grp){
        floatx4 s = {0,0,0,0};
        s = MFMA_BF16(k0, qb[grp][0], s, 0,0,0);
        s = MFMA_BF16(k1, qb[grp][1], s, 0,0,0);
        float p0 = (kg+0 < 77) ? __builtin_amdgcn_exp2f(s[0]) : 0.f;
        float p1 = (kg+1 < 77) ? __builtin_amdgcn_exp2f(s[1]) : 0.f;
        float p2 = (kg+2 < 77) ? __builtin_amdgcn_exp2f(s[2]) : 0.f;
        float p3 = (kg+3 < 77) ? __builtin_amdgcn_exp2f(s[3]) : 0.f;
        lr[grp] += (p0+p1)+(p2+p3);
        uint2 pu; pu.x = pack_bf(p0,p1); pu.y = pack_bf(p2,p3);
        short4v pb = __builtin_bit_cast(short4v, pu);
        #pragma unroll
        for(int dc=0; dc<4; ++dc)
          o[grp][dc] = MFMA16(va[dc], pb, o[grp][dc]);
      }
    }
  }
  #pragma unroll
  for(int grp=0; grp<2; ++grp){
    float lt = lr[grp];
    lt += __shfl_xor(lt, 16); lt += __shfl_xor(lt, 32);
    float inv = __builtin_amdgcn_rcpf(lt);
    size_t orow = qbase + grp*16;
    unsigned short* op = O + orow*512 + head*64 + quad*4;
    #pragma unroll
    for(int dc=0; dc<4; ++dc){
      uint2 pk;
      pk.x = pack_bf(o[grp][dc][0]*inv, o[grp][dc][1]*inv);
      pk.y = pack_bf(o[grp][dc][2]*inv, o[grp][dc][3]*inv);
      *(uint2*)(op + dc*16) = pk;
    }
  }
}

extern "C" void kernel_launch(void* const* d_in, const int* in_sizes, int n_in,
                              void* d_out, int out_size, void* d_ws, size_t ws_size,
                              hipStream_t stream) {
  const float* x        = (const float*)d_in[0];
  const float* ctx      = (const float*)d_in[1];
  const float* gn1w     = (const float*)d_in[2];
  const float* gn1b     = (const float*)d_in[3];
  const float* gn2w     = (const float*)d_in[4];
  const float* gn2b     = (const float*)d_in[5];
  const float* sa_lnv_w = (const float*)d_in[6];
  const float* sa_lnv_b = (const float*)d_in[7];
  const float* sa_lnl_w = (const float*)d_in[8];
  const float* sa_lnl_b = (const float*)d_in[9];
  const float* sa_qw    = (const float*)d_in[10];
  const float* sa_qb    = (const float*)d_in[11];
  const float* sa_kw    = (const float*)d_in[12];
  const float* sa_kb    = (const float*)d_in[13];
  const float* sa_vw    = (const float*)d_in[14];
  const float* sa_vb    = (const float*)d_in[15];
  const float* sa_ow    = (const float*)d_in[16];
  const float* sa_ob    = (const float*)d_in[17];
  const float* sa_gamma = (const float*)d_in[18];
  const float* ca_lnv_w = (const float*)d_in[19];
  const float* ca_lnv_b = (const float*)d_in[20];
  const float* ca_lnl_w = (const float*)d_in[21];
  const float* ca_lnl_b = (const float*)d_in[22];
  const float* ca_qw    = (const float*)d_in[23];
  const float* ca_qb    = (const float*)d_in[24];
  const float* ca_kw    = (const float*)d_in[25];
  const float* ca_kb    = (const float*)d_in[26];
  const float* ca_vw    = (const float*)d_in[27];
  const float* ca_vb    = (const float*)d_in[28];
  const float* ca_ow    = (const float*)d_in[29];
  const float* ca_ob    = (const float*)d_in[30];
  const float* ca_gamma = (const float*)d_in[31];

  const size_t BIGF = (size_t)16384*512*4;   // 33.55 MB
  const size_t BIGH = (size_t)16384*512*2;   // 16.78 MB
  char* w8 = (char*)d_ws;
  float*          xs   = (float*)(w8);                          // f32 GN1 output
  unsigned short* xs2b = (unsigned short*)(w8 + BIGF);          // bf16 spatial-block output
  unsigned short* vnb  = (unsigned short*)(w8 + 2*BIGF);        // later vn2b
  unsigned short* lnlb = (unsigned short*)(w8 + 2*BIGF + 1*BIGH);
  unsigned short* Qb   = (unsigned short*)(w8 + 2*BIGF + 2*BIGH);
  unsigned short* Kb   = (unsigned short*)(w8 + 2*BIGF + 3*BIGH);
  unsigned short* VTb  = (unsigned short*)(w8 + 2*BIGF + 4*BIGH);  // V^T [(bf)*512+c][1024]
  unsigned short* Ob   = (unsigned short*)(w8 + 2*BIGF + 5*BIGH);
  char* small = w8 + 2*BIGF + 6*BIGH;
  float*          st   = (float*)(small);                 // raw GN2 sums (4 KB)
  unsigned short* ctxb = (unsigned short*)(small + 4096); // 154*512*2
  unsigned short* Wb   = (unsigned short*)(small + 4096 + 157696); // 8 x 512x512 bf16
  // K2b / V2T alias the xs buffer (xs dead after the sa O-projection)
  unsigned short* K2b  = (unsigned short*)(w8);
  unsigned short* V2T  = (unsigned short*)(w8 + 1048576);   // 2*512*128 bf16

  const float QS = 0.125f * LOG2E;   // fold softmax log2e into Q scale (exp2 path)

  (void)hipMemsetAsync(st, 0, 4096, stream);
  cvtw_kernel<<<dim3(256,8),256,0,stream>>>(sa_qw, sa_kw, sa_vw, sa_ow, ca_qw, ca_kw, ca_vw, ca_ow, Wb);
  gn1_kernel<<<dim3(32,16),256,0,stream>>>(x, gn1w, gn1b, xs);
  ln_dual_kernel<<<4096,256,0,stream>>>(xs, sa_lnv_w, sa_lnv_b, sa_lnl_w, sa_lnl_b, vnb, lnlb);
  gemm64_kernel<0><<<dim3(256,2),256,0,stream>>>(vnb,  Wb+0*262144, sa_qb, 16384, QS,   Qb, nullptr, nullptr, nullptr, nullptr, nullptr);
  gemm64_kernel<0><<<dim3(256,2),256,0,stream>>>(lnlb, Wb+1*262144, sa_kb, 16384, 1.0f, Kb, nullptr, nullptr, nullptr, nullptr, nullptr);
  gemm64_kernel<3><<<dim3(256,2),256,0,stream>>>(lnlb, Wb+2*262144, sa_vb, 16384, 1.0f, VTb, nullptr, nullptr, nullptr, nullptr, nullptr);
  attn_sp_kernel<<<1024,256,0,stream>>>(Qb, Kb, VTb, Ob);
  gemm64_kernel<1><<<dim3(256,2),256,0,stream>>>(Ob, Wb+3*262144, sa_ob, 16384, 1.0f, xs2b, nullptr, xs, vnb, sa_gamma, st);
  gn2ln_kernel<<<4096,256,0,stream>>>(xs2b, st, gn2w, gn2b, ca_lnv_w, ca_lnv_b, vnb);
  ctxln_kernel<<<39,256,0,stream>>>(ctx, ca_lnl_w, ca_lnl_b, ctxb);
  gemm64_kernel<0><<<dim3(3,2),256,0,stream>>>(ctxb, Wb+5*262144, ca_kb, 154, 1.0f, K2b, nullptr, nullptr, nullptr, nullptr, nullptr);
  (void)hipMemsetAsync(V2T, 0, (size_t)2*512*128*2, stream);
  gemm64_kernel<4><<<dim3(3,2),256,0,stream>>>(ctxb, Wb+6*262144, ca_vb, 154, 1.0f, V2T, nullptr, nullptr, nullptr, nullptr, nullptr);
  gemm64_kernel<0><<<dim3(256,2),256,0,stream>>>(vnb, Wb+4*262144, ca_qb, 16384, QS, Qb, nullptr, nullptr, nullptr, nullptr, nullptr);
  attn_ca_kernel<<<1024,256,0,stream>>>(Qb, K2b, V2T, Ob);
  gemm64_kernel<2><<<dim3(256,2),256,0,stream>>>(Ob, Wb+7*262144, ca_ob, 16384, 1.0f, nullptr, (float*)d_out, nullptr, vnb, ca_gamma, nullptr);
}